// Round 9
// baseline (121.671 us; speedup 1.0000x reference)
//
#include <hip/hip_runtime.h>

// Edge detector stencil, reference: _get_edges with NTR=4, DTR=0.0, DELTA=3.
// Input  x: [16, 3, 512, 512] f32 -> 48 planes 512x512.
// Output  : [16, 24, 512, 512] f32 = [48][8][512][512] flat.
//
// Two-phase split (r8 post-mortem: plain stores reach 6.85 TB/s only with
// no concurrent read stream; NT stores cap ~5 TB/s regardless of org):
//  k1: stencil compute, pack 8 bools/px into 1 byte -> ws (12.6 MB).
//  k2: expand bits -> 403 MB, PLAIN dwordx4 stores in exact linear fill
//      order; reads only 12.6 MB (8x reused, L2/MALL-resident).

#define IMG_H 512
#define IMG_W 512

typedef float float4v __attribute__((ext_vector_type(4)));
typedef float float2v __attribute__((ext_vector_type(2)));

// Per-pixel edge mask (bits 0..7 = planes 0..7), no boundary gating.
__device__ __forceinline__ unsigned edge_mask(
    float pcc, float pmm, float pm0, float pmp,
    float p0m, float p0p, float ppm, float pp0, float ppp,
    float p0mm, float pmm0, float pmmmm, float pppmm)
{
    float d10   = pm0 - pcc;
    float d01   = p0m - pcc;
    float d11   = pmm - pcc;
    float dn11  = ppm - pcc;

    float a10 = fabsf(d10),  an10  = fabsf(pp0 - pcc);
    float a01 = fabsf(d01),  an01  = fabsf(p0p - pcc);
    float a11 = fabsf(d11),  ann11 = fabsf(ppp - pcc);
    float an11 = fabsf(dn11), a1n1 = fabsf(pmp - pcc);

    int c10 = (int)(a10 > a01) + (int)(a10 > an01) + (int)(a10 > an10)
            + 2 * (int)(a10 > fabsf(pmm - pm0))
            + (int)(a10 > fabsf(pmp - pm0));

    int c01 = (int)(a01 > a10) + (int)(a01 > an10) + (int)(a01 > an01)
            + (int)(a01 > fabsf(pmm - p0m))
            + (int)(a01 > fabsf(ppm - p0m))
            + (int)(a01 > fabsf(p0mm - p0m));

    int c11 = (int)(a11 > an11) + (int)(a11 > a1n1) + (int)(a11 > ann11)
            + (int)(a11 > fabsf(p0mm - pmm))
            + (int)(a11 > fabsf(pmm0 - pmm))
            + (int)(a11 > fabsf(pmmmm - pmm));

    int cn11 = (int)(an11 > a11) + (int)(an11 > a1n1) + (int)(an11 > ann11)
             + (int)(an11 > fabsf(p0mm - ppm))
             + 2 * (int)(an11 > fabsf(pppmm - ppm));

    unsigned m = 0;
    m |= (c10  > 4 && d10  > 0.f) ? 1u   : 0u;
    m |= (c10  > 4 && d10  < 0.f) ? 2u   : 0u;
    m |= (c01  > 4 && d01  > 0.f) ? 4u   : 0u;
    m |= (c01  > 4 && d01  < 0.f) ? 8u   : 0u;
    m |= (c11  > 4 && d11  > 0.f) ? 16u  : 0u;
    m |= (c11  > 4 && d11  < 0.f) ? 32u  : 0u;
    m |= (cn11 > 4 && dn11 > 0.f) ? 64u  : 0u;
    m |= (cn11 > 4 && dn11 < 0.f) ? 128u : 0u;
    return m;
}

// k1: compute + pack. thread = (n, h, w0=wq*4); ws32[idx] = 4 bytes = 4 px.
__global__ __launch_bounds__(256) void edge_pack_kernel(
    const float* __restrict__ in, unsigned* __restrict__ ws)
{
    int idx = blockIdx.x * blockDim.x + threadIdx.x;
    int wq = idx & (IMG_W / 4 - 1);
    int h = (idx >> 7) & (IMG_H - 1);
    int n = idx >> 16;
    int w0 = wq * 4;

    const float* img = in + (size_t)n * IMG_H * IMG_W;

    const float* rM2 = img + max(h - 2, 0) * IMG_W;
    const float* rM1 = img + max(h - 1, 0) * IMG_W;
    const float* R0  = img + h * IMG_W;
    const float* rP1 = img + min(h + 1, IMG_H - 1) * IMG_W;
    const float* rP2 = img + min(h + 2, IMG_H - 1) * IMG_W;

    bool vm2 = (h >= 2), vm1 = (h >= 1);
    bool vp1 = (h <= IMG_H - 2), vp2 = (h <= IMG_H - 3);
    bool vl = (w0 != 0);
    bool vr = (w0 != IMG_W - 4);
    int cl2 = max(w0 - 2, 0);
    int cl1 = max(w0 - 1, 0);
    int cr4 = min(w0 + 4, IMG_W - 1);

    float4v m_m2 = *(const float4v*)(rM2 + w0);
    float4v m_m1 = *(const float4v*)(rM1 + w0);
    float4v m_0  = *(const float4v*)(R0  + w0);
    float4v m_p1 = *(const float4v*)(rP1 + w0);
    float2v m_p2 = *(const float2v*)(rP2 + w0);

    float rm2[6], rm1[6], r0[7], rp1[6], rp2[4];

    rm2[0] = (vm2 && vl) ? rM2[cl2] : 1.0f;
    rm2[1] = (vm2 && vl) ? rM2[cl1] : 1.0f;
#pragma unroll
    for (int j = 0; j < 4; ++j) rm2[j + 2] = vm2 ? m_m2[j] : 1.0f;

    rm1[0] = (vm1 && vl) ? rM1[cl1] : 1.0f;
#pragma unroll
    for (int j = 0; j < 4; ++j) rm1[j + 1] = vm1 ? m_m1[j] : 1.0f;
    rm1[5] = (vm1 && vr) ? rM1[cr4] : 1.0f;

    r0[0] = vl ? R0[cl2] : 1.0f;
    r0[1] = vl ? R0[cl1] : 1.0f;
#pragma unroll
    for (int j = 0; j < 4; ++j) r0[j + 2] = m_0[j];
    r0[6] = vr ? R0[cr4] : 1.0f;

    rp1[0] = (vp1 && vl) ? rP1[cl1] : 1.0f;
#pragma unroll
    for (int j = 0; j < 4; ++j) rp1[j + 1] = vp1 ? m_p1[j] : 1.0f;
    rp1[5] = (vp1 && vr) ? rP1[cr4] : 1.0f;

    rp2[0] = (vp2 && vl) ? rP2[cl2] : 1.0f;
    rp2[1] = (vp2 && vl) ? rP2[cl1] : 1.0f;
    rp2[2] = vp2 ? m_p2[0] : 1.0f;
    rp2[3] = vp2 ? m_p2[1] : 1.0f;

    bool hge2 = (h >= 2), hlt = (h < IMG_H - 2);
    unsigned gh = (hge2 ? 0x11u : 0u)      // bits 0,4
                | (hlt  ? 0x62u : 0u)      // bits 1,5,6
                | (hge2 ? 0x80u : 0u)      // bit 7
                | (hlt  ? 0x20u : 0u);     // (bit5 already; harmless)
    // gh: bit0=hge2, bit1=hlt, bit2/3=always, bit4=hge2, bit5=hlt,
    //     bit6=hlt, bit7=hge2
    gh = (hge2 ? 0x91u : 0u) | (hlt ? 0x62u : 0u) | 0x0Cu;

    unsigned pk = 0;
#pragma unroll
    for (int i = 0; i < 4; ++i) {
        unsigned m = edge_mask(
            r0[i + 2],
            rm1[i], rm1[i + 1], rm1[i + 2],
            r0[i + 1], r0[i + 3],
            rp1[i], rp1[i + 1], rp1[i + 2],
            r0[i],
            rm2[i + 2],
            rm2[i],
            rp2[i]);
        int w = w0 + i;
        bool wge2 = (w >= 2), wlt = (w < IMG_W - 2);
        // bit2=wge2, bit3=wlt, bit4=wge2, bit5=wlt, bit6=wge2, bit7=wlt
        unsigned gw = 0x03u | (wge2 ? 0x54u : 0u) | (wlt ? 0xA8u : 0u);
        m &= gh & gw;
        pk |= m << (8 * i);
    }
    ws[idx] = pk;
}

// k2: expand bits -> floats, exact linear fill order, PLAIN dwordx4 stores.
// f = float4 index into out. f = ((n*8+p)*512 + h)*128 + q.
__global__ __launch_bounds__(256) void edge_expand_kernel(
    const unsigned* __restrict__ ws, float* __restrict__ out)
{
    int f = blockIdx.x * blockDim.x + threadIdx.x;
    int q = f & 127;
    int h = (f >> 7) & (IMG_H - 1);
    int p = (f >> 16) & 7;
    int n = f >> 19;

    unsigned pk = ws[((n << 9) | h) << 7 | q];

    float4v v;
    v[0] = ((pk >> p)        & 1u) ? 1.f : 0.f;
    v[1] = ((pk >> (8 + p))  & 1u) ? 1.f : 0.f;
    v[2] = ((pk >> (16 + p)) & 1u) ? 1.f : 0.f;
    v[3] = ((pk >> (24 + p)) & 1u) ? 1.f : 0.f;

    ((float4v*)out)[f] = v;
}

extern "C" void kernel_launch(void* const* d_in, const int* in_sizes, int n_in,
                              void* d_out, int out_size, void* d_ws, size_t ws_size,
                              hipStream_t stream) {
    const float* x = (const float*)d_in[0];
    float* out = (float*)d_out;
    unsigned* ws = (unsigned*)d_ws;
    int nimg = in_sizes[0] / (IMG_H * IMG_W);                 // 48
    int grid1 = nimg * IMG_H * (IMG_W / 4) / 256;             // 12,288
    edge_pack_kernel<<<grid1, 256, 0, stream>>>(x, ws);
    int grid2 = out_size / 4 / 256;                           // 98,304
    edge_expand_kernel<<<grid2, 256, 0, stream>>>(ws, out);
}

// Round 10
// 109.016 us; speedup vs baseline: 1.1161x; 1.1161x over previous
//
#include <hip/hip_runtime.h>

// Edge detector stencil, reference: _get_edges with NTR=4, DTR=0.0, DELTA=3.
// Input  x: [16, 3, 512, 512] f32  -> 48 planes of 512x512.
// Output  : [16, 24, 512, 512] f32 = [48, 8, 512, 512] flat.
//
// Evidence so far:
//  - plain stores: always-RFO (r5=131us, r8=113us, r9k2 slow even w/o reads)
//  - nt stores: no RFO but no merging either (r3: exact 2x sector amp on
//    strided); all organizations pin at 82.3-82.9us (~4.9 TB/s write-side)
// This round: THIRD flavor via inline asm — global_store_dwordx4 ... sc1
// (system scope = bypass L2, allocate in memory-side MALL, which can
// write-combine + batch-schedule HBM writebacks like the 6.85 TB/s fill).
// Everything else identical to round 6 (branchless best-known compute).

#define IMG_H 512
#define IMG_W 512

typedef float float4v __attribute__((ext_vector_type(4)));
typedef float float2v __attribute__((ext_vector_type(2)));

__device__ __forceinline__ void edge_core(
    float pcc, float pmm, float pm0, float pmp,
    float p0m, float p0p, float ppm, float pp0, float ppp,
    float p0mm, float pmm0, float pmmmm, float pppmm,
    float o[8])
{
    float d10   = pm0 - pcc;
    float dn10  = pp0 - pcc;
    float d01   = p0m - pcc;
    float dn01  = p0p - pcc;
    float d11   = pmm - pcc;
    float dnn11 = ppp - pcc;
    float dn11  = ppm - pcc;
    float d1n1  = pmp - pcc;

    float a10 = fabsf(d10),  an10  = fabsf(dn10);
    float a01 = fabsf(d01),  an01  = fabsf(dn01);
    float a11 = fabsf(d11),  ann11 = fabsf(dnn11);
    float an11 = fabsf(dn11), a1n1 = fabsf(d1n1);

    int c10 = (int)(a10 > a01) + (int)(a10 > an01) + (int)(a10 > an10)
            + 2 * (int)(a10 > fabsf(pmm - pm0))
            + (int)(a10 > fabsf(pmp - pm0));

    int c01 = (int)(a01 > a10) + (int)(a01 > an10) + (int)(a01 > an01)
            + (int)(a01 > fabsf(pmm - p0m))
            + (int)(a01 > fabsf(ppm - p0m))
            + (int)(a01 > fabsf(p0mm - p0m));

    int c11 = (int)(a11 > an11) + (int)(a11 > a1n1) + (int)(a11 > ann11)
            + (int)(a11 > fabsf(p0mm - pmm))
            + (int)(a11 > fabsf(pmm0 - pmm))
            + (int)(a11 > fabsf(pmmmm - pmm));

    int cn11 = (int)(an11 > a11) + (int)(an11 > a1n1) + (int)(an11 > ann11)
             + (int)(an11 > fabsf(p0mm - ppm))
             + 2 * (int)(an11 > fabsf(pppmm - ppm));

    o[0] = (c10 > 4 && d10 > 0.f) ? 1.f : 0.f;
    o[1] = (c10 > 4 && d10 < 0.f) ? 1.f : 0.f;
    o[2] = (c01 > 4 && d01 > 0.f) ? 1.f : 0.f;
    o[3] = (c01 > 4 && d01 < 0.f) ? 1.f : 0.f;
    o[4] = (c11 > 4 && d11 > 0.f) ? 1.f : 0.f;
    o[5] = (c11 > 4 && d11 < 0.f) ? 1.f : 0.f;
    o[6] = (cn11 > 4 && dn11 > 0.f) ? 1.f : 0.f;
    o[7] = (cn11 > 4 && dn11 < 0.f) ? 1.f : 0.f;
}

__global__ __launch_bounds__(256) void edge_kernel(const float* __restrict__ in,
                                                   float* __restrict__ out,
                                                   int nimg) {
    int idx = blockIdx.x * blockDim.x + threadIdx.x;
    int wq = idx & (IMG_W / 4 - 1);      // 0..127
    int h = (idx >> 7) & (IMG_H - 1);
    int n = idx >> 16;
    if (n >= nimg) return;
    int w0 = wq * 4;

    const float* img = in + (size_t)n * IMG_H * IMG_W;

    // Clamped row pointers + validity flags (uniform, no branch).
    const float* rM2 = img + max(h - 2, 0) * IMG_W;
    const float* rM1 = img + max(h - 1, 0) * IMG_W;
    const float* R0  = img + h * IMG_W;
    const float* rP1 = img + min(h + 1, IMG_H - 1) * IMG_W;
    const float* rP2 = img + min(h + 2, IMG_H - 1) * IMG_W;

    bool vm2 = (h >= 2), vm1 = (h >= 1);
    bool vp1 = (h <= IMG_H - 2), vp2 = (h <= IMG_H - 3);
    bool vl = (w0 != 0);
    bool vr = (w0 != IMG_W - 4);
    int cl2 = max(w0 - 2, 0);
    int cl1 = max(w0 - 1, 0);
    int cr4 = min(w0 + 4, IMG_W - 1);

    float4v m_m2 = *(const float4v*)(rM2 + w0);
    float4v m_m1 = *(const float4v*)(rM1 + w0);
    float4v m_0  = *(const float4v*)(R0  + w0);
    float4v m_p1 = *(const float4v*)(rP1 + w0);
    float2v m_p2 = *(const float2v*)(rP2 + w0);

    float rm2[6], rm1[6], r0[7], rp1[6], rp2[4];

    rm2[0] = (vm2 && vl) ? rM2[cl2] : 1.0f;
    rm2[1] = (vm2 && vl) ? rM2[cl1] : 1.0f;
#pragma unroll
    for (int j = 0; j < 4; ++j) rm2[j + 2] = vm2 ? m_m2[j] : 1.0f;

    rm1[0] = (vm1 && vl) ? rM1[cl1] : 1.0f;
#pragma unroll
    for (int j = 0; j < 4; ++j) rm1[j + 1] = vm1 ? m_m1[j] : 1.0f;
    rm1[5] = (vm1 && vr) ? rM1[cr4] : 1.0f;

    r0[0] = vl ? R0[cl2] : 1.0f;
    r0[1] = vl ? R0[cl1] : 1.0f;
#pragma unroll
    for (int j = 0; j < 4; ++j) r0[j + 2] = m_0[j];
    r0[6] = vr ? R0[cr4] : 1.0f;

    rp1[0] = (vp1 && vl) ? rP1[cl1] : 1.0f;
#pragma unroll
    for (int j = 0; j < 4; ++j) rp1[j + 1] = vp1 ? m_p1[j] : 1.0f;
    rp1[5] = (vp1 && vr) ? rP1[cr4] : 1.0f;

    rp2[0] = (vp2 && vl) ? rP2[cl2] : 1.0f;
    rp2[1] = (vp2 && vl) ? rP2[cl1] : 1.0f;
    rp2[2] = vp2 ? m_p2[0] : 1.0f;
    rp2[3] = vp2 ? m_p2[1] : 1.0f;

    float4v ov[8];
    bool hge2 = (h >= 2), hlt = (h < IMG_H - 2);

#pragma unroll
    for (int i = 0; i < 4; ++i) {
        float o[8];
        edge_core(r0[i + 2],                         // pcc
                  rm1[i], rm1[i + 1], rm1[i + 2],    // pmm, pm0, pmp
                  r0[i + 1], r0[i + 3],              // p0m, p0p
                  rp1[i], rp1[i + 1], rp1[i + 2],    // ppm, pp0, ppp
                  r0[i],                             // p0mm  (w-2)
                  rm2[i + 2],                        // pmm0  (h-2, w)
                  rm2[i],                            // pmmmm (h-2, w-2)
                  rp2[i],                            // pppmm (h+2, w-2)
                  o);
        int w = w0 + i;
        bool wge2 = (w >= 2), wlt = (w < IMG_W - 2);
        ov[0][i] = hge2           ? o[0] : 0.f;
        ov[1][i] = hlt            ? o[1] : 0.f;
        ov[2][i] = wge2           ? o[2] : 0.f;
        ov[3][i] = wlt            ? o[3] : 0.f;
        ov[4][i] = (hge2 && wge2) ? o[4] : 0.f;
        ov[5][i] = (hlt && wlt)   ? o[5] : 0.f;
        ov[6][i] = (hlt && wge2)  ? o[6] : 0.f;
        ov[7][i] = (hge2 && wlt)  ? o[7] : 0.f;
    }

    const size_t cs = (size_t)IMG_H * IMG_W;
    float* obase = out + ((size_t)n * 8) * cs + (size_t)h * IMG_W + w0;
#pragma unroll
    for (int k = 0; k < 8; ++k) {
        float* p = obase + (size_t)k * cs;
        // sc1 = system-scope store: bypass L2, allocate in MALL (write-
        // combining memory-side cache), unlike nt (full bypass, no merge).
        asm volatile("global_store_dwordx4 %0, %1, off sc1"
                     :: "v"(p), "v"(ov[k]) : "memory");
    }
}

extern "C" void kernel_launch(void* const* d_in, const int* in_sizes, int n_in,
                              void* d_out, int out_size, void* d_ws, size_t ws_size,
                              hipStream_t stream) {
    const float* x = (const float*)d_in[0];
    float* out = (float*)d_out;
    int nimg = in_sizes[0] / (IMG_H * IMG_W);            // 48
    long long total = (long long)nimg * IMG_H * (IMG_W / 4);  // threads
    int block = 256;
    int grid = (int)((total + block - 1) / block);
    edge_kernel<<<grid, block, 0, stream>>>(x, out, nimg);
}

// Round 11
// 82.123 us; speedup vs baseline: 1.4816x; 1.3275x over previous
//
#include <hip/hip_runtime.h>

// Edge detector stencil, reference: _get_edges with NTR=4, DTR=0.0, DELTA=3.
// Input  x: [16, 3, 512, 512] f32  -> 48 planes of 512x512.
// Output  : [16, 24, 512, 512] f32 = [48, 8, 512, 512] flat.
//
// FINAL (revert to round-7 best, 82.3us = 5.50 TB/s effective):
//  - store flavor axis mapped: plain=RFO (131us), sc1=partial (109us),
//    nt=no-RFO fastest (82.3us). nt it is.
//  - store organization axis mapped: 1KB interleaved / 4KB wave-owned /
//    LDS-staged all 82.3-82.9us -> organization-insensitive.
//  - compute axis mapped: divergent vs branchless vs LDS-staged within
//    0.8% -> memory-bound, not issue-bound.
// Kernel: block = 2 rows of one plane; branchless halo compute (r6);
// LDS-staged write phase, each wave owns one plane per 4-plane phase and
// issues 4 back-to-back dense 1KB NT stores (4KB linear run per stream).

#define IMG_H 512
#define IMG_W 512

typedef float float4v __attribute__((ext_vector_type(4)));
typedef float float2v __attribute__((ext_vector_type(2)));

__device__ __forceinline__ void edge_core(
    float pcc, float pmm, float pm0, float pmp,
    float p0m, float p0p, float ppm, float pp0, float ppp,
    float p0mm, float pmm0, float pmmmm, float pppmm,
    float o[8])
{
    float d10   = pm0 - pcc;
    float dn10  = pp0 - pcc;
    float d01   = p0m - pcc;
    float dn01  = p0p - pcc;
    float d11   = pmm - pcc;
    float dnn11 = ppp - pcc;
    float dn11  = ppm - pcc;
    float d1n1  = pmp - pcc;

    float a10 = fabsf(d10),  an10  = fabsf(dn10);
    float a01 = fabsf(d01),  an01  = fabsf(dn01);
    float a11 = fabsf(d11),  ann11 = fabsf(dnn11);
    float an11 = fabsf(dn11), a1n1 = fabsf(d1n1);

    int c10 = (int)(a10 > a01) + (int)(a10 > an01) + (int)(a10 > an10)
            + 2 * (int)(a10 > fabsf(pmm - pm0))
            + (int)(a10 > fabsf(pmp - pm0));

    int c01 = (int)(a01 > a10) + (int)(a01 > an10) + (int)(a01 > an01)
            + (int)(a01 > fabsf(pmm - p0m))
            + (int)(a01 > fabsf(ppm - p0m))
            + (int)(a01 > fabsf(p0mm - p0m));

    int c11 = (int)(a11 > an11) + (int)(a11 > a1n1) + (int)(a11 > ann11)
            + (int)(a11 > fabsf(p0mm - pmm))
            + (int)(a11 > fabsf(pmm0 - pmm))
            + (int)(a11 > fabsf(pmmmm - pmm));

    int cn11 = (int)(an11 > a11) + (int)(an11 > a1n1) + (int)(an11 > ann11)
             + (int)(an11 > fabsf(p0mm - ppm))
             + 2 * (int)(an11 > fabsf(pppmm - ppm));

    o[0] = (c10 > 4 && d10 > 0.f) ? 1.f : 0.f;
    o[1] = (c10 > 4 && d10 < 0.f) ? 1.f : 0.f;
    o[2] = (c01 > 4 && d01 > 0.f) ? 1.f : 0.f;
    o[3] = (c01 > 4 && d01 < 0.f) ? 1.f : 0.f;
    o[4] = (c11 > 4 && d11 > 0.f) ? 1.f : 0.f;
    o[5] = (c11 > 4 && d11 < 0.f) ? 1.f : 0.f;
    o[6] = (cn11 > 4 && dn11 > 0.f) ? 1.f : 0.f;
    o[7] = (cn11 > 4 && dn11 < 0.f) ? 1.f : 0.f;
}

__global__ __launch_bounds__(256) void edge_kernel(const float* __restrict__ in,
                                                   float* __restrict__ out) {
    // Block = plane n, rows h0..h0+1 (exact grid: 48 * 256 blocks).
    int bid = blockIdx.x;
    int n   = bid >> 8;              // 0..47
    int h0  = (bid & 255) * 2;       // 0..510
    int tid = threadIdx.x;
    int h   = h0 + (tid >> 7);       // this thread's row
    int w0  = (tid & 127) * 4;       // this thread's 4-px group

    const float* img = in + (size_t)n * IMG_H * IMG_W;

    // ---- compute phase (branchless, round-6 structure) ----
    const float* rM2 = img + max(h - 2, 0) * IMG_W;
    const float* rM1 = img + max(h - 1, 0) * IMG_W;
    const float* R0  = img + h * IMG_W;
    const float* rP1 = img + min(h + 1, IMG_H - 1) * IMG_W;
    const float* rP2 = img + min(h + 2, IMG_H - 1) * IMG_W;

    bool vm2 = (h >= 2), vm1 = (h >= 1);
    bool vp1 = (h <= IMG_H - 2), vp2 = (h <= IMG_H - 3);
    bool vl = (w0 != 0);
    bool vr = (w0 != IMG_W - 4);
    int cl2 = max(w0 - 2, 0);
    int cl1 = max(w0 - 1, 0);
    int cr4 = min(w0 + 4, IMG_W - 1);

    float4v m_m2 = *(const float4v*)(rM2 + w0);
    float4v m_m1 = *(const float4v*)(rM1 + w0);
    float4v m_0  = *(const float4v*)(R0  + w0);
    float4v m_p1 = *(const float4v*)(rP1 + w0);
    float2v m_p2 = *(const float2v*)(rP2 + w0);

    float rm2[6], rm1[6], r0[7], rp1[6], rp2[4];

    rm2[0] = (vm2 && vl) ? rM2[cl2] : 1.0f;
    rm2[1] = (vm2 && vl) ? rM2[cl1] : 1.0f;
#pragma unroll
    for (int j = 0; j < 4; ++j) rm2[j + 2] = vm2 ? m_m2[j] : 1.0f;

    rm1[0] = (vm1 && vl) ? rM1[cl1] : 1.0f;
#pragma unroll
    for (int j = 0; j < 4; ++j) rm1[j + 1] = vm1 ? m_m1[j] : 1.0f;
    rm1[5] = (vm1 && vr) ? rM1[cr4] : 1.0f;

    r0[0] = vl ? R0[cl2] : 1.0f;
    r0[1] = vl ? R0[cl1] : 1.0f;
#pragma unroll
    for (int j = 0; j < 4; ++j) r0[j + 2] = m_0[j];
    r0[6] = vr ? R0[cr4] : 1.0f;

    rp1[0] = (vp1 && vl) ? rP1[cl1] : 1.0f;
#pragma unroll
    for (int j = 0; j < 4; ++j) rp1[j + 1] = vp1 ? m_p1[j] : 1.0f;
    rp1[5] = (vp1 && vr) ? rP1[cr4] : 1.0f;

    rp2[0] = (vp2 && vl) ? rP2[cl2] : 1.0f;
    rp2[1] = (vp2 && vl) ? rP2[cl1] : 1.0f;
    rp2[2] = vp2 ? m_p2[0] : 1.0f;
    rp2[3] = vp2 ? m_p2[1] : 1.0f;

    float4v ov[8];
    bool hge2 = (h >= 2), hlt = (h < IMG_H - 2);

#pragma unroll
    for (int i = 0; i < 4; ++i) {
        float o[8];
        edge_core(r0[i + 2],
                  rm1[i], rm1[i + 1], rm1[i + 2],
                  r0[i + 1], r0[i + 3],
                  rp1[i], rp1[i + 1], rp1[i + 2],
                  r0[i],
                  rm2[i + 2],
                  rm2[i],
                  rp2[i],
                  o);
        int w = w0 + i;
        bool wge2 = (w >= 2), wlt = (w < IMG_W - 2);
        ov[0][i] = hge2           ? o[0] : 0.f;
        ov[1][i] = hlt            ? o[1] : 0.f;
        ov[2][i] = wge2           ? o[2] : 0.f;
        ov[3][i] = wlt            ? o[3] : 0.f;
        ov[4][i] = (hge2 && wge2) ? o[4] : 0.f;
        ov[5][i] = (hlt && wlt)   ? o[5] : 0.f;
        ov[6][i] = (hlt && wge2)  ? o[6] : 0.f;
        ov[7][i] = (hge2 && wlt)  ? o[7] : 0.f;
    }

    // ---- LDS-staged write phase: each wave owns one plane per phase ----
    __shared__ float4v lds[4][256];          // 16KB: 4 planes per phase

    const size_t cs = (size_t)IMG_H * IMG_W;
    float* oblk = out + ((size_t)n * 8) * cs + (size_t)h0 * IMG_W;
    int wave = tid >> 6;                     // 0..3: plane within phase
    int lane = tid & 63;

#pragma unroll
    for (int phase = 0; phase < 2; ++phase) {
        if (phase) __syncthreads();          // protect LDS reuse
#pragma unroll
        for (int j = 0; j < 4; ++j)
            lds[j][tid] = ov[phase * 4 + j];
        __syncthreads();
        int p = phase * 4 + wave;            // this wave's plane
        float* pdst = oblk + (size_t)p * cs;
#pragma unroll
        for (int c = 0; c < 4; ++c) {
            float4v v = lds[wave][c * 64 + lane];
            __builtin_nontemporal_store(
                v, (float4v*)(pdst + (size_t)(c * 64 + lane) * 4));
        }
    }
}

extern "C" void kernel_launch(void* const* d_in, const int* in_sizes, int n_in,
                              void* d_out, int out_size, void* d_ws, size_t ws_size,
                              hipStream_t stream) {
    const float* x = (const float*)d_in[0];
    float* out = (float*)d_out;
    int nimg = in_sizes[0] / (IMG_H * IMG_W);   // 48
    int grid = nimg * (IMG_H / 2);              // 12,288 blocks, exact
    edge_kernel<<<grid, 256, 0, stream>>>(x, out);
}